// Round 9
// baseline (32.154 us; speedup 1.0000x reference)
//
#include <hip/hip_runtime.h>
#include <hip/hip_fp16.h>

// NEAT sparse MLP fwd. LAYER_SIZES=[256,512,512,512,512,64], FAN_IN=32, BATCH=2048.
// OFFSETS=[0,256,768,1280,1792,2304,2368]; E_TOT=67584.
//
// R9 = R8 unchanged + PROBE: neat_fwd launched TWICE (identical, idempotent).
// Purpose: bisect the 21 us total into fwd_cost vs fixed overhead.
// dur_us(R9) - dur_us(R8) = one warm fwd dispatch.

typedef _Float16 half8_t  __attribute__((ext_vector_type(8)));
typedef float    float8_t __attribute__((ext_vector_type(8)));

constexpr int TB    = 8;
constexpr int BLOCK = 512;
constexpr int E_TOT = 67584;

__global__ __launch_bounds__(256) void pack_edges(const int* __restrict__ src,
                                                  const float* __restrict__ w,
                                                  unsigned* __restrict__ rec)
{
    const int o = blockIdx.x * 256 + threadIdx.x;
    if (o >= E_TOT) return;
    int eid, offPrev;
    if (o < 65536) {
        const int layer = o >> 14;
        const int e0    = layer << 14;
        offPrev = (layer == 0) ? 0 : (256 + (layer - 1) * 512);
        const int ol = o - e0;
        const int q = ol & 3, t = ol >> 2;
        const int i = t & 63, c = (t >> 6) & 7, g = t >> 9;
        eid = e0 + (g * 64 + i) * 32 + c * 4 + q;
    } else {
        offPrev = 1792;
        eid = o;
    }
    const unsigned off = (unsigned)(src[eid] - offPrev) * 16u;
    const unsigned hw  = (unsigned)__half_as_ushort(__float2half(w[eid]));
    rec[o] = off | (hw << 16);
}

__device__ __forceinline__ float sigmoidf(float s)
{
    return __fdividef(1.0f, 1.0f + __expf(-s));
}

template<bool PACKED>
__global__ __launch_bounds__(BLOCK) void neat_fwd(
    const float* __restrict__ x,
    const float* __restrict__ w,
    const int*   __restrict__ src,
    const int4*  __restrict__ rp,
    float*       __restrict__ out)
{
    __shared__ __align__(16) _Float16 bufA[512 * TB];
    __shared__ __align__(16) _Float16 bufB[512 * TB];

    const int tid    = threadIdx.x;
    const int batch0 = blockIdx.x * TB;
    const int base   = (tid >> 6) * 512 + (tid & 63);

    int4 rcur[8], rnxt[8];
    if (PACKED) {
#pragma unroll
        for (int c = 0; c < 8; ++c) rcur[c] = rp[base + c * 64];
    }

    {
        const int r  = tid >> 6;
        const int c4 = (tid & 63) * 4;
        const float4 v = *(const float4*)(x + (size_t)(batch0 + r) * 256 + c4);
        bufA[(c4 + 0) * TB + r] = (_Float16)v.x;
        bufA[(c4 + 1) * TB + r] = (_Float16)v.y;
        bufA[(c4 + 2) * TB + r] = (_Float16)v.z;
        bufA[(c4 + 3) * TB + r] = (_Float16)v.w;
    }
    __syncthreads();

    _Float16* prev = bufA;
    _Float16* cur  = bufB;

#define EDGE(RR, ACC)                                                          \
    do {                                                                       \
        const unsigned rr = (unsigned)(RR);                                    \
        const float wf = __half2float(__ushort_as_half((unsigned short)(rr >> 16))); \
        const half8_t a = *(const half8_t*)(pv + (rr & 0xffffu));              \
        _Pragma("unroll")                                                      \
        for (int k = 0; k < 8; ++k)                                            \
            ACC[k] = fmaf((float)a[k], wf, ACC[k]);                            \
    } while (0)

#define EDGE_RAW(SRCID, WF, ACC)                                               \
    do {                                                                       \
        const float wf = (WF);                                                 \
        const half8_t a = *(const half8_t*)(pv + (unsigned)((SRCID) - offPrev) * 16u); \
        _Pragma("unroll")                                                      \
        for (int k = 0; k < 8; ++k)                                            \
            ACC[k] = fmaf((float)a[k], wf, ACC[k]);                            \
    } while (0)

#pragma unroll
    for (int l = 0; l < 4; ++l) {
        if (PACKED) {
            if (l < 3) {
                const int4* rn = rp + (l + 1) * 4096;
#pragma unroll
                for (int c = 0; c < 8; ++c) rnxt[c] = rn[base + c * 64];
            } else {
                rnxt[0] = rp[16384 + tid];
            }
        }

        const char* pv = (const char*)prev;
        float8_t acc = {0.f, 0.f, 0.f, 0.f, 0.f, 0.f, 0.f, 0.f};
        if (PACKED) {
#pragma unroll
            for (int c = 0; c < 8; ++c) {
                const int4 r4 = rcur[c];
                EDGE(r4.x, acc);
                EDGE(r4.y, acc);
                EDGE(r4.z, acc);
                EDGE(r4.w, acc);
            }
        } else {
            const int e0 = l * 16384;
            const int offPrev = (l == 0) ? 0 : (256 + (l - 1) * 512);
            const int ebase = e0 + tid * 32;
#pragma unroll
            for (int c = 0; c < 8; ++c) {
                const int4   s4 = *(const int4*)(src + ebase + c * 4);
                const float4 w4 = *(const float4*)(w + ebase + c * 4);
                EDGE_RAW(s4.x, w4.x, acc);
                EDGE_RAW(s4.y, w4.y, acc);
                EDGE_RAW(s4.z, w4.z, acc);
                EDGE_RAW(s4.w, w4.w, acc);
            }
        }

        half8_t r;
#pragma unroll
        for (int k = 0; k < 8; ++k)
            r[k] = (_Float16)sigmoidf(acc[k]);
        *(half8_t*)(cur + tid * TB) = r;
        __syncthreads();
        _Float16* t = prev; prev = cur; cur = t;

        if (PACKED) {
#pragma unroll
            for (int c = 0; c < 8; ++c) rcur[c] = rnxt[c];
        }
    }

    {
        const char* pv = (const char*)prev;
        float8_t acc = {0.f, 0.f, 0.f, 0.f, 0.f, 0.f, 0.f, 0.f};
        if (PACKED) {
            const int4 r4 = rcur[0];
            EDGE(r4.x, acc);
            EDGE(r4.y, acc);
            EDGE(r4.z, acc);
            EDGE(r4.w, acc);
        } else {
            const int offPrev = 1792;
            const int eb = 65536 + tid * 4;
            const int4   s4 = *(const int4*)(src + eb);
            const float4 w4 = *(const float4*)(w + eb);
            EDGE_RAW(s4.x, w4.x, acc);
            EDGE_RAW(s4.y, w4.y, acc);
            EDGE_RAW(s4.z, w4.z, acc);
            EDGE_RAW(s4.w, w4.w, acc);
        }
#pragma unroll
        for (int m = 1; m <= 4; m <<= 1) {
#pragma unroll
            for (int k = 0; k < 8; ++k)
                acc[k] += __shfl_xor(acc[k], m, 64);
        }
        if ((tid & 7) == 0) {
            const int n = tid >> 3;
#pragma unroll
            for (int b = 0; b < 8; ++b)
                out[(size_t)(batch0 + b) * 64 + n] = sigmoidf(acc[b]);
        }
    }
#undef EDGE
#undef EDGE_RAW
}

extern "C" void kernel_launch(void* const* d_in, const int* in_sizes, int n_in,
                              void* d_out, int out_size, void* d_ws, size_t ws_size,
                              hipStream_t stream)
{
    const float* x   = (const float*)d_in[0];
    const float* w   = (const float*)d_in[1];
    const int*   src = (const int*)d_in[2];
    float* out = (float*)d_out;

    const int batch = in_sizes[0] / 256;   // 2048
    const int grid  = batch / TB;          // 256

    unsigned* rec = (unsigned*)d_ws;

    if (ws_size >= (size_t)E_TOT * 4) {
        pack_edges<<<(E_TOT + 255) / 256, 256, 0, stream>>>(src, w, rec);
        // PROBE: two identical, idempotent fwd launches. The second's marginal
        // cost == one warm fwd dispatch; dur_us(R9)-dur_us(R8) isolates it.
        neat_fwd<true><<<grid, BLOCK, 0, stream>>>(x, w, src, (const int4*)rec, out);
        neat_fwd<true><<<grid, BLOCK, 0, stream>>>(x, w, src, (const int4*)rec, out);
    } else {
        neat_fwd<false><<<grid, BLOCK, 0, stream>>>(x, w, src, (const int4*)rec, out);
        neat_fwd<false><<<grid, BLOCK, 0, stream>>>(x, w, src, (const int4*)rec, out);
    }
}

// Round 10
// 21.160 us; speedup vs baseline: 1.5196x; 1.5196x over previous
//
#include <hip/hip_runtime.h>
#include <hip/hip_fp16.h>

// NEAT sparse MLP fwd. LAYER_SIZES=[256,512,512,512,512,64], FAN_IN=32, BATCH=2048.
// OFFSETS=[0,256,768,1280,1792,2304,2368]; E_TOT=67584.
//
// R10 = R8 fwd (best) + INVERTED pack: iterate raw edge-quads so src/w reads
// are perfectly coalesced (int4/float4), scatter the 16-B record writes
// instead (writes have no exposed latency). R9 probe showed fwd ~11 us and
// ~10 us pack+launch overhead; pack's 64-line-per-wave reads were the suspect.

typedef _Float16 half8_t  __attribute__((ext_vector_type(8)));
typedef float    float8_t __attribute__((ext_vector_type(8)));

constexpr int TB    = 8;
constexpr int BLOCK = 512;
constexpr int E_TOT = 67584;   // 16896 quads = 66 * 256

__global__ __launch_bounds__(256) void pack_edges(const int4* __restrict__ s4,
                                                  const float4* __restrict__ w4,
                                                  uint4* __restrict__ rec4)
{
    const int v = blockIdx.x * 256 + threadIdx.x;   // edge-quad id, [0, 16896)
    const int4   s = s4[v];   // coalesced
    const float4 ww = w4[v];  // coalesced

    int offPrev, dst;
    if (v < 16384) {
        const int layer = v >> 12;
        offPrev = (layer == 0) ? 0 : (256 + (layer - 1) * 512);
        const int vl = v & 4095;
        const int n  = vl >> 3;          // node within layer
        const int c  = vl & 7;           // chunk
        const int g  = n >> 6, i = n & 63;
        dst = (layer << 12) + (g * 8 + c) * 64 + i;   // uint4 index
    } else {
        offPrev = 1792;
        dst = v;                          // layer-5 identity
    }

    uint4 r;
    r.x = ((unsigned)(s.x - offPrev) * 16u) | ((unsigned)__half_as_ushort(__float2half(ww.x)) << 16);
    r.y = ((unsigned)(s.y - offPrev) * 16u) | ((unsigned)__half_as_ushort(__float2half(ww.y)) << 16);
    r.z = ((unsigned)(s.z - offPrev) * 16u) | ((unsigned)__half_as_ushort(__float2half(ww.z)) << 16);
    r.w = ((unsigned)(s.w - offPrev) * 16u) | ((unsigned)__half_as_ushort(__float2half(ww.w)) << 16);
    rec4[dst] = r;
}

__device__ __forceinline__ float sigmoidf(float s)
{
    return __fdividef(1.0f, 1.0f + __expf(-s));
}

template<bool PACKED>
__global__ __launch_bounds__(BLOCK) void neat_fwd(
    const float* __restrict__ x,
    const float* __restrict__ w,
    const int*   __restrict__ src,
    const int4*  __restrict__ rp,
    float*       __restrict__ out)
{
    __shared__ __align__(16) _Float16 bufA[512 * TB];
    __shared__ __align__(16) _Float16 bufB[512 * TB];

    const int tid    = threadIdx.x;
    const int batch0 = blockIdx.x * TB;
    const int base   = (tid >> 6) * 512 + (tid & 63);

    int4 rcur[8], rnxt[8];
    if (PACKED) {
#pragma unroll
        for (int c = 0; c < 8; ++c) rcur[c] = rp[base + c * 64];
    }

    {
        const int r  = tid >> 6;
        const int c4 = (tid & 63) * 4;
        const float4 v = *(const float4*)(x + (size_t)(batch0 + r) * 256 + c4);
        bufA[(c4 + 0) * TB + r] = (_Float16)v.x;
        bufA[(c4 + 1) * TB + r] = (_Float16)v.y;
        bufA[(c4 + 2) * TB + r] = (_Float16)v.z;
        bufA[(c4 + 3) * TB + r] = (_Float16)v.w;
    }
    __syncthreads();

    _Float16* prev = bufA;
    _Float16* cur  = bufB;

#define EDGE(RR, ACC)                                                          \
    do {                                                                       \
        const unsigned rr = (unsigned)(RR);                                    \
        const float wf = __half2float(__ushort_as_half((unsigned short)(rr >> 16))); \
        const half8_t a = *(const half8_t*)(pv + (rr & 0xffffu));              \
        _Pragma("unroll")                                                      \
        for (int k = 0; k < 8; ++k)                                            \
            ACC[k] = fmaf((float)a[k], wf, ACC[k]);                            \
    } while (0)

#define EDGE_RAW(SRCID, WF, ACC)                                               \
    do {                                                                       \
        const float wf = (WF);                                                 \
        const half8_t a = *(const half8_t*)(pv + (unsigned)((SRCID) - offPrev) * 16u); \
        _Pragma("unroll")                                                      \
        for (int k = 0; k < 8; ++k)                                            \
            ACC[k] = fmaf((float)a[k], wf, ACC[k]);                            \
    } while (0)

#pragma unroll
    for (int l = 0; l < 4; ++l) {
        if (PACKED) {
            if (l < 3) {
                const int4* rn = rp + (l + 1) * 4096;
#pragma unroll
                for (int c = 0; c < 8; ++c) rnxt[c] = rn[base + c * 64];
            } else {
                rnxt[0] = rp[16384 + tid];
            }
        }

        const char* pv = (const char*)prev;
        float8_t acc = {0.f, 0.f, 0.f, 0.f, 0.f, 0.f, 0.f, 0.f};
        if (PACKED) {
#pragma unroll
            for (int c = 0; c < 8; ++c) {
                const int4 r4 = rcur[c];
                EDGE(r4.x, acc);
                EDGE(r4.y, acc);
                EDGE(r4.z, acc);
                EDGE(r4.w, acc);
            }
        } else {
            const int e0 = l * 16384;
            const int offPrev = (l == 0) ? 0 : (256 + (l - 1) * 512);
            const int ebase = e0 + tid * 32;
#pragma unroll
            for (int c = 0; c < 8; ++c) {
                const int4   s4 = *(const int4*)(src + ebase + c * 4);
                const float4 w4 = *(const float4*)(w + ebase + c * 4);
                EDGE_RAW(s4.x, w4.x, acc);
                EDGE_RAW(s4.y, w4.y, acc);
                EDGE_RAW(s4.z, w4.z, acc);
                EDGE_RAW(s4.w, w4.w, acc);
            }
        }

        half8_t r;
#pragma unroll
        for (int k = 0; k < 8; ++k)
            r[k] = (_Float16)sigmoidf(acc[k]);
        *(half8_t*)(cur + tid * TB) = r;
        __syncthreads();
        _Float16* t = prev; prev = cur; cur = t;

        if (PACKED) {
#pragma unroll
            for (int c = 0; c < 8; ++c) rcur[c] = rnxt[c];
        }
    }

    // Layer 5: n = tid>>3, c = tid&7; 8 partials per node in 8 consecutive
    // lanes -> shfl_xor reduce, no LDS scratch.
    {
        const char* pv = (const char*)prev;
        float8_t acc = {0.f, 0.f, 0.f, 0.f, 0.f, 0.f, 0.f, 0.f};
        if (PACKED) {
            const int4 r4 = rcur[0];
            EDGE(r4.x, acc);
            EDGE(r4.y, acc);
            EDGE(r4.z, acc);
            EDGE(r4.w, acc);
        } else {
            const int offPrev = 1792;
            const int eb = 65536 + tid * 4;
            const int4   s4 = *(const int4*)(src + eb);
            const float4 w4 = *(const float4*)(w + eb);
            EDGE_RAW(s4.x, w4.x, acc);
            EDGE_RAW(s4.y, w4.y, acc);
            EDGE_RAW(s4.z, w4.z, acc);
            EDGE_RAW(s4.w, w4.w, acc);
        }
#pragma unroll
        for (int m = 1; m <= 4; m <<= 1) {
#pragma unroll
            for (int k = 0; k < 8; ++k)
                acc[k] += __shfl_xor(acc[k], m, 64);
        }
        if ((tid & 7) == 0) {
            const int n = tid >> 3;
#pragma unroll
            for (int b = 0; b < 8; ++b)
                out[(size_t)(batch0 + b) * 64 + n] = sigmoidf(acc[b]);
        }
    }
#undef EDGE
#undef EDGE_RAW
}

extern "C" void kernel_launch(void* const* d_in, const int* in_sizes, int n_in,
                              void* d_out, int out_size, void* d_ws, size_t ws_size,
                              hipStream_t stream)
{
    const float* x   = (const float*)d_in[0];
    const float* w   = (const float*)d_in[1];
    const int*   src = (const int*)d_in[2];
    float* out = (float*)d_out;

    const int batch = in_sizes[0] / 256;   // 2048
    const int grid  = batch / TB;          // 256

    unsigned* rec = (unsigned*)d_ws;

    if (ws_size >= (size_t)E_TOT * 4) {
        pack_edges<<<E_TOT / 4 / 256, 256, 0, stream>>>(
            (const int4*)src, (const float4*)w, (uint4*)rec);
        neat_fwd<true><<<grid, BLOCK, 0, stream>>>(x, w, src, (const int4*)rec, out);
    } else {
        neat_fwd<false><<<grid, BLOCK, 0, stream>>>(x, w, src, (const int4*)rec, out);
    }
}